// Round 11
// baseline (119.162 us; speedup 1.0000x reference)
//
#include <hip/hip_runtime.h>
#include <stdint.h>

#define NPTS 2048

// ---- workspace layout (bytes) ----
// Bp fragment-ordered (R4-verified): [z][qb=16][s=64][frag 1KB]; frag slot L holds
// (q-col n=L>>2, k-range (L&3)*8..+8). Reader lane (quad,n) -> offset n*64+quad*16.
#define BP_OFF    0ULL
#define BP_BYTES  (8ULL * 16 * 64 * 1024)      // 8 MB
#define W2F_OFF   (BP_OFF + BP_BYTES)
#define W2F_BYTES (24ULL * 1024)               // frags kb0..5 x cb0..3
#define WXF_OFF   (W2F_OFF + W2F_BYTES)
#define WXF_BYTES (24ULL * 1024)               // frags kb0..1 x cb0..11
// Mask words: [z][at=32][kw=64][64 dwords]; dword n*4+rg = word for row rg*16+n.
#define MW_OFF    (WXF_OFF + WXF_BYTES)
#define MW_BYTES  (8ULL * 32 * 64 * 256)       // 4 MB  (total ~12.4 MB)

typedef __attribute__((ext_vector_type(8))) short bf16x8;
typedef __attribute__((ext_vector_type(4))) float f32x4;
typedef __attribute__((ext_vector_type(4))) unsigned int u32x4;
typedef __attribute__((ext_vector_type(2))) unsigned int u32x2;

__device__ __forceinline__ unsigned f2bf(float f) {
  union { float f; unsigned u; } v; v.f = f;
  return (v.u + 0x7FFFu + ((v.u >> 16) & 1u)) >> 16;  // RNE
}

__device__ __forceinline__ bf16x8 pack8(const float4 a, const float4 b) {
  u32x4 r;
  r[0] = f2bf(a.x) | (f2bf(a.y) << 16);
  r[1] = f2bf(a.z) | (f2bf(a.w) << 16);
  r[2] = f2bf(b.x) | (f2bf(b.y) << 16);
  r[3] = f2bf(b.z) | (f2bf(b.w) << 16);
  union { u32x4 u; bf16x8 h; } c; c.u = r; return c.h;
}

// 8 mask bits -> 8 bf16 (1.0/0.0): bit-deposit mul + v_perm + mul. (R9/R10-verified)
__device__ __forceinline__ bf16x8 unpack_mask(unsigned mq) {
  const unsigned dep0 = ((mq & 15u) * 0x204081u) & 0x01010101u;        // bits0-3 -> bytes
  const unsigned dep1 = (((mq >> 4) & 15u) * 0x204081u) & 0x01010101u; // bits4-7
  u32x4 aw;
  aw[0] = __builtin_amdgcn_perm(dep0, 0u, 0x0C050C04u) * 0x3F80u;
  aw[1] = __builtin_amdgcn_perm(dep0, 0u, 0x0C070C06u) * 0x3F80u;
  aw[2] = __builtin_amdgcn_perm(dep1, 0u, 0x0C050C04u) * 0x3F80u;
  aw[3] = __builtin_amdgcn_perm(dep1, 0u, 0x0C070C06u) * 0x3F80u;
  union { u32x4 u; bf16x8 h; } cv; cv.u = aw;
  return cv.h;
}

// ========== K1: Bp frags + weight frags + mask bitwords (R9/R10 verbatim — verified) ==========
__global__ __launch_bounds__(256, 2) void k1_prep(const float* __restrict__ feat,
                                                  const float* __restrict__ geom,
                                                  const float* __restrict__ Wk,
                                                  unsigned char* __restrict__ ws) {
  const int blk = blockIdx.x, t = threadIdx.x;
  if (blk < 512) {
    const int z = blk >> 6, s = blk & 63;       // 32 b-points per s-chunk
    __shared__ float FT[64][37];                // F^T[j][k]
    __shared__ float g[96];                     // b-geometry [32][3]
    __shared__ float gxp[2048], gyp[2048], gzp[2048];  // z geometry, swizzled p'=(p&7)*256+(p>>3)
    const float* fz = feat + ((size_t)z * NPTS + s * 32) * 64;
    const float* gz = geom + (size_t)z * NPTS * 3;
    {
      const int row = t >> 3, j0 = (t & 7) << 3;
      const float4 v0 = *(const float4*)&fz[row * 64 + j0];
      const float4 v1 = *(const float4*)&fz[row * 64 + j0 + 4];
      FT[j0 + 0][row] = v0.x; FT[j0 + 1][row] = v0.y;
      FT[j0 + 2][row] = v0.z; FT[j0 + 3][row] = v0.w;
      FT[j0 + 4][row] = v1.x; FT[j0 + 5][row] = v1.y;
      FT[j0 + 6][row] = v1.z; FT[j0 + 7][row] = v1.w;
    }
    if (t < 96) g[t] = gz[s * 96 + t];
    {  // stage geometry planes: thread reads 24 contiguous floats (8 points)
      float v[24];
#pragma unroll
      for (int i = 0; i < 6; ++i) *(float4*)&v[i * 4] = *(const float4*)&gz[t * 24 + i * 4];
#pragma unroll
      for (int i = 0; i < 8; ++i) {
        const int pp = i * 256 + t;             // swizzled slot (conflict-free)
        gxp[pp] = v[i * 3 + 0]; gyp[pp] = v[i * 3 + 1]; gzp[pp] = v[i * 3 + 2];
      }
    }
    __syncthreads();

    {  // ---- Bp build (R4 verbatim) ----
      const int w = t >> 6, L = t & 63;
      const int nn = L >> 2, k0 = (L & 3) * 8;
      const int j = w * 16 + nn;
      float f[8];
#pragma unroll
      for (int i = 0; i < 8; ++i) f[i] = FT[j][k0 + i];
      float gx[3][8];
#pragma unroll
      for (int x = 0; x < 3; ++x)
#pragma unroll
        for (int i = 0; i < 8; ++i) gx[x][i] = g[(k0 + i) * 3 + x];
      unsigned char* base = ws + BP_OFF + (size_t)z * 1048576 + (size_t)w * 65536 +
                            (size_t)s * 1024 + L * 16;
#pragma unroll
      for (int it = 0; it < 4; ++it) {          // x = it; frag qb = it*4 + w
        u32x4 pv;
#pragma unroll
        for (int p = 0; p < 4; ++p) {
          float f0 = f[2 * p], f1 = f[2 * p + 1];
          if (it < 3) { f0 *= gx[it][2 * p]; f1 *= gx[it][2 * p + 1]; }
          pv[p] = f2bf(f0) | (f2bf(f1) << 16);
        }
        *(u32x4*)(base + (size_t)it * 4 * 65536) = pv;
      }
    }

    {  // ---- mask bitwords: rows t*8..+8 vs b = s*32..+32 ----
      float ax[8], ay[8], az[8];
#pragma unroll
      for (int i = 0; i < 8; ++i) {
        const int pp = i * 256 + t;
        ax[i] = gxp[pp]; ay[i] = gyp[pp]; az[i] = gzp[pp];
      }
      unsigned bits[8] = {0, 0, 0, 0, 0, 0, 0, 0};
      for (int j = 0; j < 32; ++j) {
        const float bx = g[j * 3 + 0], by = g[j * 3 + 1], bz = g[j * 3 + 2];
#pragma unroll
        for (int i = 0; i < 8; ++i) {
          const float d0 = bx - ax[i], d1 = by - ay[i], d2 = bz - az[i];
          const float n2 = fmaf(d2, d2, fmaf(d1, d1, d0 * d0));
          bits[i] |= (n2 < 1.0f ? 1u : 0u) << j;
        }
      }
      unsigned int* mw = (unsigned int*)(ws + MW_OFF);
#pragma unroll
      for (int i = 0; i < 8; ++i) {
        const int r = t * 8 + i;
        mw[(((size_t)z * 32 + (r >> 6)) * 64 + s) * 64 + (r & 15) * 4 + ((r >> 4) & 3)] = bits[i];
      }
    }
  } else if (blk == 512) {   // W2F frags
    for (int e = t; e < 1536; e += 256) {
      const int frag = e >> 6, lp = e & 63, nn = lp >> 2, qd = lp & 3;
      const int kb = frag >> 2, cb = frag & 3;
      u32x4 pv;
#pragma unroll
      for (int p = 0; p < 4; ++p) {
        const int k0 = kb * 32 + qd * 8 + 2 * p;
        const float v0 = Wk[(k0 >> 6) * 4096 + (cb * 16 + nn) * 64 + (k0 & 63)];
        const float v1 = Wk[((k0 + 1) >> 6) * 4096 + (cb * 16 + nn) * 64 + ((k0 + 1) & 63)];
        pv[p] = f2bf(v0) | (f2bf(v1) << 16);
      }
      *(u32x4*)(ws + W2F_OFF + (size_t)frag * 1024 + lp * 16) = pv;
    }
  } else {                   // WXF frags
    for (int e = t; e < 1536; e += 256) {
      const int frag = e >> 6, lp = e & 63, nn = lp >> 2, qd = lp & 3;
      const int kb = frag / 12, cb = frag % 12, xi = cb * 16 + nn;
      u32x4 pv;
#pragma unroll
      for (int p = 0; p < 4; ++p) {
        const int k0 = kb * 32 + qd * 8 + 2 * p;
        const float v0 = Wk[(xi >> 6) * 4096 + (xi & 63) * 64 + k0];
        const float v1 = Wk[(xi >> 6) * 4096 + (xi & 63) * 64 + k0 + 1];
        pv[p] = f2bf(v0) | (f2bf(v1) << 16);
      }
      *(u32x4*)(ws + WXF_OFF + (size_t)frag * 1024 + lp * 16) = pv;
    }
  }
}

// ========== K2: mask-GEMM at 4 waves/SIMD, imm-offset streams, no clamps ==========
// grid 256 = (z = bx&7, at = bx>>3). 1024 thr = 16 waves = 4/SIMD.
// Wave w: h = w&1 (rows 32h..+32), c = w>>1 (cols 32c..+32; qb = 2c, 2c+1).
// 2 unpacks : 4 MFMAs per step; 3 stream pointers bumped once per 4-step group,
// loads at compile-time imm offsets. Prefetch overrun past step 63 lands in unused ws.
__global__ __launch_bounds__(1024, 4) void k2_gemm(const float* __restrict__ geom,
                                                   const unsigned char* __restrict__ ws,
                                                   float* __restrict__ out) {
  __shared__ __align__(16) float Ct[64 * 256];            // 64 KB

  const int t = threadIdx.x, lane = t & 63, w = t >> 6;   // w = 0..15
  const int quad = (lane >> 4) & 3, n = lane & 15;
  const int bx = blockIdx.x;
  const int z = bx & 7, at = bx >> 3, a0 = at * 64;
  const int fragoff = n * 64 + quad * 16;
  const int qsh = quad * 8;
  const int h = w & 1, c = w >> 1;

  const unsigned char* bp0 = ws + BP_OFF + (size_t)z * 1048576 +
                             (size_t)(2 * c) * 65536 + fragoff;
  const unsigned char* bp1 = bp0 + 65536;
  const unsigned char* mp = ws + MW_OFF + ((size_t)z * 32 + at) * 16384 + n * 16 + 8 * h;

  f32x4 acc[2][2];
#pragma unroll
  for (int rg = 0; rg < 2; ++rg)
#pragma unroll
    for (int cb = 0; cb < 2; ++cb)
#pragma unroll
      for (int r = 0; r < 4; ++r) acc[rg][cb][r] = 0.f;

  bf16x8 Bf[4][2];                              // 4-deep pipeline
  u32x2 Mf[4];
#pragma unroll
  for (int sl = 0; sl < 4; ++sl) {
    Bf[sl][0] = *(const bf16x8*)(bp0 + sl * 1024);
    Bf[sl][1] = *(const bf16x8*)(bp1 + sl * 1024);
    Mf[sl] = *(const u32x2*)(mp + sl * 256);
  }

#define KSTEP(SL)                                                              \
  {                                                                            \
    const u32x2 mw = Mf[SL];                                                   \
    const bf16x8 Af0 = unpack_mask(mw[0] >> qsh);                              \
    const bf16x8 Af1 = unpack_mask(mw[1] >> qsh);                              \
    acc[0][0] = __builtin_amdgcn_mfma_f32_16x16x32_bf16(Af0, Bf[SL][0],        \
                                                        acc[0][0], 0, 0, 0);   \
    acc[0][1] = __builtin_amdgcn_mfma_f32_16x16x32_bf16(Af0, Bf[SL][1],        \
                                                        acc[0][1], 0, 0, 0);   \
    acc[1][0] = __builtin_amdgcn_mfma_f32_16x16x32_bf16(Af1, Bf[SL][0],        \
                                                        acc[1][0], 0, 0, 0);   \
    acc[1][1] = __builtin_amdgcn_mfma_f32_16x16x32_bf16(Af1, Bf[SL][1],        \
                                                        acc[1][1], 0, 0, 0);   \
    Mf[SL] = *(const u32x2*)(mp + SL * 256);                                   \
    Bf[SL][0] = *(const bf16x8*)(bp0 + SL * 1024);                             \
    Bf[SL][1] = *(const bf16x8*)(bp1 + SL * 1024);                             \
  }

  for (int s4 = 0; s4 < 64; s4 += 4) {
    bp0 += 4096; bp1 += 4096; mp += 1024;       // point at s4+4 (prefetch group)
    KSTEP(0) KSTEP(1) KSTEP(2) KSTEP(3)
  }
#undef KSTEP

  // ---- epilogue: acc -> Ct fp32 (R4 XOR swizzle) ----
#pragma unroll
  for (int rg = 0; rg < 2; ++rg)
#pragma unroll
    for (int cb = 0; cb < 2; ++cb)
#pragma unroll
      for (int r = 0; r < 4; ++r) {
        const int row = 32 * h + rg * 16 + quad * 4 + r;   // C/D: row = quad*4+r
        const int col = (2 * c + cb) * 16 + n;             // C/D: col = n
        Ct[row * 256 + (((col >> 2) ^ row) << 2) + (col & 3)] = acc[rg][cb][r];
      }
  __syncthreads();

  if (w < 4) {
    const int lm = 16 * w + n;                             // final-GEMM A row
    bf16x8 Across[8];
#pragma unroll
    for (int kb = 0; kb < 8; ++kb) {
      const int c0 = (kb * 8 + quad * 2) ^ lm;
      const int c1 = (kb * 8 + quad * 2 + 1) ^ lm;
      const float4 f0 = *(const float4*)&Ct[lm * 256 + c0 * 4];
      const float4 f1 = *(const float4*)&Ct[lm * 256 + c1 * 4];
      Across[kb] = pack8(f0, f1);
    }

    f32x4 mn[4], V[12];
#pragma unroll
    for (int i = 0; i < 4; ++i)
#pragma unroll
      for (int r = 0; r < 4; ++r) mn[i][r] = 0.f;
#pragma unroll
    for (int i = 0; i < 12; ++i)
#pragma unroll
      for (int r = 0; r < 4; ++r) V[i][r] = 0.f;

    const unsigned char* w2f = ws + W2F_OFF;
    const unsigned char* wxf = ws + WXF_OFF;
#pragma unroll
    for (int kb = 0; kb < 6; ++kb)
#pragma unroll
      for (int cb = 0; cb < 4; ++cb) {
        const bf16x8 Bfr = *(const bf16x8*)(w2f + (size_t)(kb * 4 + cb) * 1024 + fragoff);
        mn[cb] = __builtin_amdgcn_mfma_f32_16x16x32_bf16(Across[kb], Bfr, mn[cb], 0, 0, 0);
      }
#pragma unroll
    for (int kb = 0; kb < 2; ++kb)
#pragma unroll
      for (int cb = 0; cb < 12; ++cb) {
        const bf16x8 Bfr = *(const bf16x8*)(wxf + (size_t)(kb * 12 + cb) * 1024 + fragoff);
        V[cb] = __builtin_amdgcn_mfma_f32_16x16x32_bf16(Across[6 + kb], Bfr, V[cb], 0, 0, 0);
      }

#pragma unroll
    for (int r = 0; r < 4; ++r) {
      const int af = a0 + 16 * w + quad * 4 + r;           // C/D row = quad*4 + r
      const float g0 = geom[((size_t)z * NPTS + af) * 3 + 0];
      const float g1 = geom[((size_t)z * NPTS + af) * 3 + 1];
      const float g2 = geom[((size_t)z * NPTS + af) * 3 + 2];
#pragma unroll
      for (int cb = 0; cb < 4; ++cb) {
        const float v = mn[cb][r] - g0 * V[cb][r] - g1 * V[cb + 4][r] - g2 * V[cb + 8][r];
        out[((size_t)z * NPTS + af) * 64 + cb * 16 + n] = v;
      }
    }
  }
}

extern "C" void kernel_launch(void* const* d_in, const int* in_sizes, int n_in,
                              void* d_out, int out_size, void* d_ws, size_t ws_size,
                              hipStream_t stream) {
  const float* feat = (const float*)d_in[0];  // [8,2048,64]
  const float* geom = (const float*)d_in[1];  // [8,2048,3]
  const float* Wk   = (const float*)d_in[2];  // [3,64,64]
  float* out = (float*)d_out;                 // [8,2048,64] fp32
  unsigned char* ws = (unsigned char*)d_ws;   // ~12.4 MB used

  k1_prep<<<dim3(514), 256, 0, stream>>>(feat, geom, Wk, ws);
  k2_gemm<<<dim3(256), 1024, 0, stream>>>(geom, ws, out);
}